// Round 9
// baseline (1363.031 us; speedup 1.0000x reference)
//
#include <hip/hip_runtime.h>
#include <hip/hip_bf16.h>
#include <math.h>

// Problem constants
#define GL 2
#define GH 128
#define GH2 256
#define GV 50257
#define GB 100
#define GT 50
#define GM 5000            // B*T rows
#define NT 393             // n tiles (128 wide): ceil(50257/128)
#define MT 40              // m tiles (128 tall): ceil(5000/128)
#define MT2 20             // m-tile PAIRS (256 tall per block)

typedef __attribute__((ext_vector_type(4))) float f32x4;
typedef __attribute__((ext_vector_type(8))) short bf16x8;

// ---------------------------------------------------------------------------
// Kernel 1: GRU. One block per batch item (r2/r5-verified version).
// ---------------------------------------------------------------------------
__global__ __launch_bounds__(1024) void gru_kernel(
    const int* __restrict__ tok,        // (B,T)
    const float* __restrict__ emb,      // (V,H)
    const float* __restrict__ gate_k,   // (L,2H,2H)
    const float* __restrict__ gate_b,   // (L,2H)
    const float* __restrict__ cand_k,   // (L,2H,H)
    const float* __restrict__ cand_b,   // (L,H)
    float* __restrict__ out)            // (B*T,H)
{
    const int b = blockIdx.x;
    const int tid = threadIdx.x;

    __shared__ float xin[GH2];
    __shared__ float hs[2][GH];
    __shared__ float g[GH2];
    __shared__ float gpart[4][GH2];
    __shared__ float cpart[8][GH];

    if (tid < GH) { hs[0][tid] = 0.f; hs[1][tid] = 0.f; }
    __syncthreads();

    for (int t = 0; t < GT; ++t) {
        const int token = tok[b * GT + t];
        if (tid < GH) xin[tid] = emb[(size_t)token * GH + tid];

        for (int l = 0; l < GL; ++l) {
            if (tid >= GH && tid < GH2) xin[tid] = hs[l][tid - GH];
            __syncthreads();

            {   // gate
                const int j  = tid & 255;
                const int t4 = tid >> 8;
                const float* gcol = gate_k + (size_t)l * GH2 * GH2 + (size_t)(t4 * 64) * GH2 + j;
                const float* xv = xin + t4 * 64;
                float acc = 0.f;
                #pragma unroll 16
                for (int i = 0; i < 64; ++i) acc += xv[i] * gcol[(size_t)i * GH2];
                gpart[t4][j] = acc;
            }
            __syncthreads();
            if (tid < GH2) {
                float s = gpart[0][tid] + gpart[1][tid] + gpart[2][tid] + gpart[3][tid]
                        + gate_b[l * GH2 + tid];
                g[tid] = 1.f / (1.f + expf(-s));
            }
            __syncthreads();
            if (tid >= GH && tid < GH2) xin[tid] = g[tid - GH] * hs[l][tid - GH];
            __syncthreads();

            {   // cand
                const int j  = tid & 127;
                const int t8 = tid >> 7;
                const float* ccol = cand_k + (size_t)l * GH2 * GH + (size_t)(t8 * 32) * GH + j;
                const float* xv = xin + t8 * 32;
                float acc = 0.f;
                #pragma unroll 16
                for (int i = 0; i < 32; ++i) acc += xv[i] * ccol[(size_t)i * GH];
                cpart[t8][j] = acc;
            }
            __syncthreads();
            if (tid < GH) {
                float csum = 0.f;
                #pragma unroll
                for (int p = 0; p < 8; ++p) csum += cpart[p][tid];
                const float c = tanhf(csum + cand_b[l * GH + tid]);
                const float u = g[GH + tid];
                const float hn = u * hs[l][tid] + (1.f - u) * c;
                hs[l][tid] = hn;
                xin[tid] = hn;
                if (l == GL - 1) out[(size_t)(b * GT + t) * GH + tid] = hn;
            }
            __syncthreads();
        }
    }
}

// ---------------------------------------------------------------------------
// bf16 split helpers
// ---------------------------------------------------------------------------
__device__ __forceinline__ unsigned short f2bf(float x) {
    union { float f; unsigned u; } c; c.f = x;
    unsigned r = c.u + 0x7FFFu + ((c.u >> 16) & 1u);   // RNE
    return (unsigned short)(r >> 16);
}
__device__ __forceinline__ float bf2f(unsigned short b) {
    union { unsigned u; float f; } c; c.u = ((unsigned)b) << 16; return c.f;
}

// ---------------------------------------------------------------------------
// Kernel 2: prep — fp32 (rows x 128) -> staged XOR-swizzled bf16 chunks.
// chunk 0: hi(k0..63)  1: hi(k64..127)  2: lo(k0..63)  3: lo(k64..127)
// (r,k) stored at r*64 + (k ^ ((r&7)<<3)): linear global_load_lds then yields
// a bank-conflict-free swizzled LDS image (swizzle source + read, rule #21).
// ---------------------------------------------------------------------------
__global__ __launch_bounds__(256) void prep_kernel(
    const float* __restrict__ src, unsigned short* __restrict__ dst,
    int ntiles, int nrows)
{
    const int idx = blockIdx.x * 256 + threadIdx.x;
    if (idx >= ntiles * 4 * 128) return;
    const int r    = idx & 127;
    const int c    = idx >> 7;
    const int cs   = c & 3;
    const int tile = c >> 2;
    int row = tile * 128 + r; if (row > nrows - 1) row = nrows - 1;
    const float* s = src + (size_t)row * GH + (cs & 1) * 64;
    unsigned short* d = dst + (size_t)c * 8192 + r * 64;
    const bool lo = (cs >= 2);
    const int rx = r & 7;

    #pragma unroll
    for (int gq = 0; gq < 8; ++gq) {
        float x[8];
        *(float4*)(x)     = *(const float4*)(s + gq * 8);
        *(float4*)(x + 4) = *(const float4*)(s + gq * 8 + 4);
        unsigned u[4];
        #pragma unroll
        for (int q = 0; q < 4; ++q) {
            const float a0 = x[q * 2], a1 = x[q * 2 + 1];
            const unsigned short hi0 = f2bf(a0), hi1 = f2bf(a1);
            unsigned short h0, h1;
            if (lo) { h0 = f2bf(a0 - bf2f(hi0)); h1 = f2bf(a1 - bf2f(hi1)); }
            else    { h0 = hi0; h1 = hi1; }
            u[q] = (unsigned)h0 | ((unsigned)h1 << 16);
        }
        *(uint4*)(d + (size_t)((gq ^ rx) * 8)) = *(const uint4*)u;
    }
}

// ---------------------------------------------------------------------------
// Kernel 3: MFMA logits GEMM, K=384 bf16 (hi*hi + hi*lo + lo*hi).
// SINGLE structural change vs r8: each block computes TWO m-tiles (256x128
// output) with 8 waves (512 thr); wave (mt,wm,wn) owns a 64x64 sub-tile of
// its m-tile -> acc stays 4x4 f32x4 = 64 VGPR. W chunks staged ONCE per
// block into a single 16 KB slot (sequenced so each stays live across its
// products); A chunks per m-tile. 6 drain-barriers per 2 output tiles
// (halved per tile vs r8), staging 96 KB/tile (-25%). LDS 52 KB;
// ~116 VGPR -> 16 waves/CU, same occupancy as r8 (unlike r3/r7's 8).
//   step:    0        1        2        3        4        5
//   stage: A0,W2     W0       A2      A1,W3     W1       A3     (A x both mt)
//   prod:  A0*W2    A0*W0    A2*W0    A1*W3    A1*W1    A3*W1
// Chunk ids: 0=hi k0..63, 1=hi k64..127, 2=lo k0..63, 3=lo k64..127.
// ---------------------------------------------------------------------------
__global__ __launch_bounds__(512, 2) void mfma_logits_kernel(
    const unsigned short* __restrict__ Ap, const unsigned short* __restrict__ Wp,
    const float* __restrict__ bias,
    float* __restrict__ logits, float* __restrict__ pmax, float* __restrict__ psum)
{
    __shared__ unsigned short ldsA[2][8192];   // one 16 KB slot per m-tile
    __shared__ unsigned short ldsW[8192];      // single 16 KB W slot
    __shared__ float sM[2][256];
    __shared__ float sS[2][256];

    const int bm  = blockIdx.x;     // m-tile PAIR (fastest -> W-tile L2 locality)
    const int bt  = blockIdx.y;     // n tile
    const int tid = threadIdx.x;
    const int wid  = tid >> 6;      // 0..7
    const int lane = tid & 63;
    const int mt = wid >> 2;        // 0..1: which m-tile this wave owns
    const int wm = (wid >> 1) & 1;  // 64-row half within m-tile
    const int wn = wid & 1;         // 64-col half
    const int l15 = lane & 15, l4 = lane >> 4;

    f32x4 acc[4][4];
    #pragma unroll
    for (int i = 0; i < 4; ++i)
        #pragma unroll
        for (int j = 0; j < 4; ++j) acc[i][j] = (f32x4){0.f, 0.f, 0.f, 0.f};

    // 512 threads stage a 16 KB chunk as 2 x dwordx4 per thread
#define STAGE_A(MT_, CH)                                                                \
    {                                                                                   \
        const unsigned short* g = Ap + (size_t)((bm * 2 + MT_) * 4 + CH) * 8192 + tid * 8; \
        __builtin_amdgcn_global_load_lds(                                               \
            (const __attribute__((address_space(1))) void*)(g),                         \
            (__attribute__((address_space(3))) void*)(&ldsA[MT_][tid * 8]), 16, 0, 0);  \
        __builtin_amdgcn_global_load_lds(                                               \
            (const __attribute__((address_space(1))) void*)(g + 4096),                  \
            (__attribute__((address_space(3))) void*)(&ldsA[MT_][tid * 8 + 4096]), 16, 0, 0); \
    }
#define STAGE_W(CH)                                                                     \
    {                                                                                   \
        const unsigned short* g = Wp + (size_t)(bt * 4 + CH) * 8192 + tid * 8;          \
        __builtin_amdgcn_global_load_lds(                                               \
            (const __attribute__((address_space(1))) void*)(g),                         \
            (__attribute__((address_space(3))) void*)(&ldsW[tid * 8]), 16, 0, 0);       \
        __builtin_amdgcn_global_load_lds(                                               \
            (const __attribute__((address_space(1))) void*)(g + 4096),                  \
            (__attribute__((address_space(3))) void*)(&ldsW[tid * 8 + 4096]), 16, 0, 0); \
    }
    // wave computes its m-tile's chunk-product from current LDS contents
#define COMPUTE                                                                         \
    {                                                                                   \
        _Pragma("unroll")                                                               \
        for (int ks = 0; ks < 2; ++ks) {                                                \
            bf16x8 af[4], bfr[4];                                                       \
            _Pragma("unroll")                                                           \
            for (int mi = 0; mi < 4; ++mi) {                                            \
                const int row = wm * 64 + mi * 16 + l15;                                \
                const int off = row * 64 + ((ks * 32 + l4 * 8) ^ ((row & 7) << 3));     \
                af[mi] = *(const bf16x8*)&ldsA[mt][off];                                \
            }                                                                           \
            _Pragma("unroll")                                                           \
            for (int nj = 0; nj < 4; ++nj) {                                            \
                const int row = wn * 64 + nj * 16 + l15;                                \
                const int off = row * 64 + ((ks * 32 + l4 * 8) ^ ((row & 7) << 3));     \
                bfr[nj] = *(const bf16x8*)&ldsW[off];                                   \
            }                                                                           \
            _Pragma("unroll")                                                           \
            for (int mi = 0; mi < 4; ++mi)                                              \
                _Pragma("unroll")                                                       \
                for (int nj = 0; nj < 4; ++nj)                                          \
                    acc[mi][nj] = __builtin_amdgcn_mfma_f32_16x16x32_bf16(              \
                        af[mi], bfr[nj], acc[mi][nj], 0, 0, 0);                         \
        }                                                                               \
    }

    STAGE_A(0, 0); STAGE_A(1, 0); STAGE_W(2);
    __syncthreads();  COMPUTE;                 // A0 * W2
    __syncthreads();  STAGE_W(0);
    __syncthreads();  COMPUTE;                 // A0 * W0
    __syncthreads();  STAGE_A(0, 2); STAGE_A(1, 2);
    __syncthreads();  COMPUTE;                 // A2 * W0
    __syncthreads();  STAGE_A(0, 1); STAGE_A(1, 1); STAGE_W(3);
    __syncthreads();  COMPUTE;                 // A1 * W3
    __syncthreads();  STAGE_W(1);
    __syncthreads();  COMPUTE;                 // A1 * W1
    __syncthreads();  STAGE_A(0, 3); STAGE_A(1, 3);
    __syncthreads();  COMPUTE;                 // A3 * W1

#undef STAGE_A
#undef STAGE_W
#undef COMPUTE

    // ---- epilogue: bias, store, per-(row, tile) softmax partials ----
    float bj[4]; bool nv[4];
    #pragma unroll
    for (int nj = 0; nj < 4; ++nj) {
        const int n = bt * 128 + wn * 64 + nj * 16 + l15;
        nv[nj] = (n < GV);
        bj[nj] = nv[nj] ? bias[n] : 0.f;
    }
    #pragma unroll
    for (int mi = 0; mi < 4; ++mi) {
        #pragma unroll
        for (int r = 0; r < 4; ++r) {
            const int rowb = mt * 128 + wm * 64 + mi * 16 + l4 * 4 + r;   // 0..255
            const int m = bm * 256 + rowb;
            float v[4];
            #pragma unroll
            for (int nj = 0; nj < 4; ++nj) v[nj] = acc[mi][nj][r] + bj[nj];
            if (m < GM) {
                #pragma unroll
                for (int nj = 0; nj < 4; ++nj)
                    if (nv[nj])
                        logits[(size_t)m * GV + (bt * 128 + wn * 64 + nj * 16 + l15)] = v[nj];
            }
            float mx = -INFINITY;
            #pragma unroll
            for (int nj = 0; nj < 4; ++nj) if (nv[nj]) mx = fmaxf(mx, v[nj]);
            #pragma unroll
            for (int d = 1; d < 16; d <<= 1) mx = fmaxf(mx, __shfl_xor(mx, d));
            float se = 0.f;
            #pragma unroll
            for (int nj = 0; nj < 4; ++nj) if (nv[nj]) se += __expf(v[nj] - mx);
            #pragma unroll
            for (int d = 1; d < 16; d <<= 1) se += __shfl_xor(se, d);
            if (l15 == 0) { sM[wn][rowb] = mx; sS[wn][rowb] = se; }
        }
    }
    __syncthreads();
    if (tid < 256) {
        const int m = bm * 256 + tid;
        if (m < GM) {
            const float m0 = sM[0][tid], m1 = sM[1][tid];
            const float M = fmaxf(m0, m1);
            const float S = sS[0][tid] * __expf(m0 - M) + sS[1][tid] * __expf(m1 - M);
            pmax[(size_t)m * NT + bt] = M;
            psum[(size_t)m * NT + bt] = S;
        }
    }
}

// ---------------------------------------------------------------------------
// Kernel 4: merge per-tile (max,sum) -> per-row (max, 1/sum). 1 wave per row.
// ---------------------------------------------------------------------------
__global__ __launch_bounds__(64) void reduce_kernel(
    const float* __restrict__ pmax, const float* __restrict__ psum,
    float* __restrict__ rowM, float* __restrict__ rowInvS)
{
    const int m = blockIdx.x;
    const int lane = threadIdx.x;
    float M = -INFINITY, S = 0.f;
    for (int t = lane; t < NT; t += 64) {
        const float m2 = pmax[(size_t)m * NT + t];
        const float s2 = psum[(size_t)m * NT + t];
        const float nM = fmaxf(M, m2);
        S = S * expf(M - nM) + s2 * expf(m2 - nM);
        M = nM;
    }
    #pragma unroll
    for (int d = 1; d < 64; d <<= 1) {
        const float m2 = __shfl_xor(M, d);
        const float s2 = __shfl_xor(S, d);
        const float nM = fmaxf(M, m2);
        S = S * expf(M - nM) + s2 * expf(m2 - nM);
        M = nM;
    }
    if (lane == 0) { rowM[m] = M; rowInvS[m] = 1.f / S; }
}

// ---------------------------------------------------------------------------
// Kernel 5: probs = exp(logits - M) * invS. float4 grid-stride.
// ---------------------------------------------------------------------------
__global__ __launch_bounds__(256) void probs_kernel(
    const float* __restrict__ logits,
    const float* __restrict__ rowM, const float* __restrict__ rowInvS,
    float* __restrict__ probs)
{
    const float4* L4 = reinterpret_cast<const float4*>(logits);
    float4* P4 = reinterpret_cast<float4*>(probs);
    const int n4 = (int)(((long long)GM * GV) / 4);
    const int stride = gridDim.x * blockDim.x;
    for (int i = blockIdx.x * blockDim.x + threadIdx.x; i < n4; i += stride) {
        const float4 v = L4[i];
        const int base = i * 4;
        const int m0 = base / GV;
        const int m3 = (base + 3) / GV;
        float4 o;
        if (m0 == m3) {
            const float M = rowM[m0], Is = rowInvS[m0];
            o.x = __expf(v.x - M) * Is;
            o.y = __expf(v.y - M) * Is;
            o.z = __expf(v.z - M) * Is;
            o.w = __expf(v.w - M) * Is;
        } else {
            const int ma = base / GV, mb = (base + 1) / GV;
            const int mc = (base + 2) / GV, md = (base + 3) / GV;
            o.x = __expf(v.x - rowM[ma]) * rowInvS[ma];
            o.y = __expf(v.y - rowM[mb]) * rowInvS[mb];
            o.z = __expf(v.z - rowM[mc]) * rowInvS[mc];
            o.w = __expf(v.w - rowM[md]) * rowInvS[md];
        }
        P4[i] = o;
    }
}

// ---------------------------------------------------------------------------
extern "C" void kernel_launch(void* const* d_in, const int* in_sizes, int n_in,
                              void* d_out, int out_size, void* d_ws, size_t ws_size,
                              hipStream_t stream) {
    const int*   tok    = (const int*)d_in[0];
    const float* emb    = (const float*)d_in[1];
    const float* gate_k = (const float*)d_in[2];
    const float* gate_b = (const float*)d_in[3];
    const float* cand_k = (const float*)d_in[4];
    const float* cand_b = (const float*)d_in[5];
    const float* W      = (const float*)d_in[6];
    const float* bias   = (const float*)d_in[7];

    float* logits = (float*)d_out;
    float* probs  = logits + (size_t)GM * GV;

    float* ws = (float*)d_ws;
    float* gruout = ws;                                        // 640,000 f32
    unsigned short* Ap = (unsigned short*)(gruout + 640000);   // 40*4*8192 bf16
    unsigned short* Wp = Ap + (size_t)MT * 4 * 8192;           // 393*4*8192 bf16
    float* pmax    = (float*)(Wp + (size_t)NT * 4 * 8192);
    float* psum    = pmax + (size_t)GM * NT;
    float* rowM    = psum + (size_t)GM * NT;
    float* rowInvS = rowM + GM;

    gru_kernel<<<GB, 1024, 0, stream>>>(tok, emb, gate_k, gate_b, cand_k, cand_b, gruout);

    prep_kernel<<<(MT * 4 * 128 + 255) / 256, 256, 0, stream>>>(gruout, Ap, MT, GM);
    prep_kernel<<<(NT * 4 * 128 + 255) / 256, 256, 0, stream>>>(W, Wp, NT, GV);

    dim3 g2(MT2, NT);   // m-pair fastest: W-tile L2/L3 locality
    mfma_logits_kernel<<<g2, 512, 0, stream>>>(Ap, Wp, bias, logits, pmax, psum);

    reduce_kernel<<<GM, 64, 0, stream>>>(pmax, psum, rowM, rowInvS);

    probs_kernel<<<4096, 256, 0, stream>>>(logits, rowM, rowInvS, probs);
}

// Round 10
// 1355.994 us; speedup vs baseline: 1.0052x; 1.0052x over previous
//
#include <hip/hip_runtime.h>
#include <hip/hip_bf16.h>
#include <math.h>

// Problem constants
#define GL 2
#define GH 128
#define GH2 256
#define GV 50257
#define GB 100
#define GT 50
#define GM 5000            // B*T rows
#define NT 393             // n tiles (128 wide): ceil(50257/128)
#define MT 40              // m tiles (128 tall): ceil(5000/128)

typedef __attribute__((ext_vector_type(4))) float f32x4;
typedef __attribute__((ext_vector_type(8))) short bf16x8;

// ---------------------------------------------------------------------------
// Kernel 1: GRU. One block per batch item (r2/r5-verified version).
// ---------------------------------------------------------------------------
__global__ __launch_bounds__(1024) void gru_kernel(
    const int* __restrict__ tok,        // (B,T)
    const float* __restrict__ emb,      // (V,H)
    const float* __restrict__ gate_k,   // (L,2H,2H)
    const float* __restrict__ gate_b,   // (L,2H)
    const float* __restrict__ cand_k,   // (L,2H,H)
    const float* __restrict__ cand_b,   // (L,H)
    float* __restrict__ out)            // (B*T,H)
{
    const int b = blockIdx.x;
    const int tid = threadIdx.x;

    __shared__ float xin[GH2];
    __shared__ float hs[2][GH];
    __shared__ float g[GH2];
    __shared__ float gpart[4][GH2];
    __shared__ float cpart[8][GH];

    if (tid < GH) { hs[0][tid] = 0.f; hs[1][tid] = 0.f; }
    __syncthreads();

    for (int t = 0; t < GT; ++t) {
        const int token = tok[b * GT + t];
        if (tid < GH) xin[tid] = emb[(size_t)token * GH + tid];

        for (int l = 0; l < GL; ++l) {
            if (tid >= GH && tid < GH2) xin[tid] = hs[l][tid - GH];
            __syncthreads();

            {   // gate
                const int j  = tid & 255;
                const int t4 = tid >> 8;
                const float* gcol = gate_k + (size_t)l * GH2 * GH2 + (size_t)(t4 * 64) * GH2 + j;
                const float* xv = xin + t4 * 64;
                float acc = 0.f;
                #pragma unroll 16
                for (int i = 0; i < 64; ++i) acc += xv[i] * gcol[(size_t)i * GH2];
                gpart[t4][j] = acc;
            }
            __syncthreads();
            if (tid < GH2) {
                float s = gpart[0][tid] + gpart[1][tid] + gpart[2][tid] + gpart[3][tid]
                        + gate_b[l * GH2 + tid];
                g[tid] = 1.f / (1.f + expf(-s));
            }
            __syncthreads();
            if (tid >= GH && tid < GH2) xin[tid] = g[tid - GH] * hs[l][tid - GH];
            __syncthreads();

            {   // cand
                const int j  = tid & 127;
                const int t8 = tid >> 7;
                const float* ccol = cand_k + (size_t)l * GH2 * GH + (size_t)(t8 * 32) * GH + j;
                const float* xv = xin + t8 * 32;
                float acc = 0.f;
                #pragma unroll 16
                for (int i = 0; i < 32; ++i) acc += xv[i] * ccol[(size_t)i * GH];
                cpart[t8][j] = acc;
            }
            __syncthreads();
            if (tid < GH) {
                float csum = 0.f;
                #pragma unroll
                for (int p = 0; p < 8; ++p) csum += cpart[p][tid];
                const float c = tanhf(csum + cand_b[l * GH + tid]);
                const float u = g[GH + tid];
                const float hn = u * hs[l][tid] + (1.f - u) * c;
                hs[l][tid] = hn;
                xin[tid] = hn;
                if (l == GL - 1) out[(size_t)(b * GT + t) * GH + tid] = hn;
            }
            __syncthreads();
        }
    }
}

// ---------------------------------------------------------------------------
// bf16 split helpers
// ---------------------------------------------------------------------------
__device__ __forceinline__ unsigned short f2bf(float x) {
    union { float f; unsigned u; } c; c.f = x;
    unsigned r = c.u + 0x7FFFu + ((c.u >> 16) & 1u);   // RNE
    return (unsigned short)(r >> 16);
}
__device__ __forceinline__ float bf2f(unsigned short b) {
    union { unsigned u; float f; } c; c.u = ((unsigned)b) << 16; return c.f;
}

// ---------------------------------------------------------------------------
// Kernel 2: prep — fp32 (rows x 128) -> staged XOR-swizzled bf16 chunks.
// chunk 0: hi(k0..63)  1: hi(k64..127)  2: lo(k0..63)  3: lo(k64..127)
// (r,k) stored at r*64 + (k ^ ((r&7)<<3)): linear global_load_lds then yields
// a bank-conflict-free swizzled LDS image (swizzle source + read, rule #21).
// ---------------------------------------------------------------------------
__global__ __launch_bounds__(256) void prep_kernel(
    const float* __restrict__ src, unsigned short* __restrict__ dst,
    int ntiles, int nrows)
{
    const int idx = blockIdx.x * 256 + threadIdx.x;
    if (idx >= ntiles * 4 * 128) return;
    const int r    = idx & 127;
    const int c    = idx >> 7;
    const int cs   = c & 3;
    const int tile = c >> 2;
    int row = tile * 128 + r; if (row > nrows - 1) row = nrows - 1;
    const float* s = src + (size_t)row * GH + (cs & 1) * 64;
    unsigned short* d = dst + (size_t)c * 8192 + r * 64;
    const bool lo = (cs >= 2);
    const int rx = r & 7;

    #pragma unroll
    for (int gq = 0; gq < 8; ++gq) {
        float x[8];
        *(float4*)(x)     = *(const float4*)(s + gq * 8);
        *(float4*)(x + 4) = *(const float4*)(s + gq * 8 + 4);
        unsigned u[4];
        #pragma unroll
        for (int q = 0; q < 4; ++q) {
            const float a0 = x[q * 2], a1 = x[q * 2 + 1];
            const unsigned short hi0 = f2bf(a0), hi1 = f2bf(a1);
            unsigned short h0, h1;
            if (lo) { h0 = f2bf(a0 - bf2f(hi0)); h1 = f2bf(a1 - bf2f(hi1)); }
            else    { h0 = hi0; h1 = hi1; }
            u[q] = (unsigned)h0 | ((unsigned)h1 << 16);
        }
        *(uint4*)(d + (size_t)((gq ^ rx) * 8)) = *(const uint4*)u;
    }
}

// ---------------------------------------------------------------------------
// Kernel 3: MFMA logits GEMM, K=384 bf16 (hi*hi + hi*lo + lo*hi), 128x128
// tile, 4 waves, single-buffered, min-staging walk (r8 base = best).
// SINGLE change vs r8: OPERAND-SWAPPED MFMA — mfma(bf, af, acc). Same
// products/accumulation order (logits bitwise-identical), but C layout
// transposes: lane now holds 4 CONSECUTIVE n-columns of one m-row
// (n = wn*64 + nj*16 + l4*4 + r, m = wm*64 + mi*16 + l15), so:
//   - stores: 16x global_store_dwordx4 per wave (was 64x dword)
//   - softmax row-stats: per-lane serial over 16 vals + 2 shfl_xor
//     (16/32) per row-group (was 128 shfl_xor per wave)
//   step:     0        1        2        3        4        5
//   prod:  Ah0*Wl0  Ah0*Wh0  Al0*Wh0  Ah1*Wl1  Ah1*Wh1  Al1*Wh1
//   stage:  A0,W2     W0       A2      A1,W3     W1       A3
// ---------------------------------------------------------------------------
__global__ __launch_bounds__(256) void mfma_logits_kernel(
    const unsigned short* __restrict__ Ap, const unsigned short* __restrict__ Wp,
    const float* __restrict__ bias,
    float* __restrict__ logits, float* __restrict__ pmax, float* __restrict__ psum)
{
    __shared__ unsigned short ldsA[8192];
    __shared__ unsigned short ldsW[8192];
    __shared__ float sM[2][128];
    __shared__ float sS[2][128];

    const int bm  = blockIdx.x;     // m tile (fastest -> W-tile L2 locality)
    const int bt  = blockIdx.y;     // n tile
    const int tid = threadIdx.x;
    const int wid  = tid >> 6;
    const int lane = tid & 63;
    const int wm = wid >> 1, wn = wid & 1;
    const int l15 = lane & 15, l4 = lane >> 4;

    // minimum-staging walk (see header comment)
    constexpr int amap[6] = {0, 0, 2, 1, 1, 3};
    constexpr int astg[6] = {1, 0, 1, 1, 0, 1};
    constexpr int wmap[6] = {2, 0, 0, 3, 1, 1};
    constexpr int wstg[6] = {1, 1, 0, 1, 1, 0};

    f32x4 acc[4][4];
    #pragma unroll
    for (int i = 0; i < 4; ++i)
        #pragma unroll
        for (int j = 0; j < 4; ++j) acc[i][j] = (f32x4){0.f, 0.f, 0.f, 0.f};

    #pragma unroll
    for (int s = 0; s < 6; ++s) {
        if (astg[s]) {
            const unsigned short* ga = Ap + (size_t)(bm * 4 + amap[s]) * 8192 + wid * 2048 + lane * 8;
            #pragma unroll
            for (int i = 0; i < 4; ++i)
                __builtin_amdgcn_global_load_lds(
                    (const __attribute__((address_space(1))) void*)(ga + i * 512),
                    (__attribute__((address_space(3))) void*)(&ldsA[wid * 2048 + i * 512]), 16, 0, 0);
        }
        if (wstg[s]) {
            const unsigned short* gw = Wp + (size_t)(bt * 4 + wmap[s]) * 8192 + wid * 2048 + lane * 8;
            #pragma unroll
            for (int i = 0; i < 4; ++i)
                __builtin_amdgcn_global_load_lds(
                    (const __attribute__((address_space(1))) void*)(gw + i * 512),
                    (__attribute__((address_space(3))) void*)(&ldsW[wid * 2048 + i * 512]), 16, 0, 0);
        }
        __syncthreads();   // drains vmcnt before barrier -> LDS image complete

        #pragma unroll
        for (int ks = 0; ks < 2; ++ks) {
            bf16x8 af[4], bf[4];
            #pragma unroll
            for (int mi = 0; mi < 4; ++mi) {
                const int row = wm * 64 + mi * 16 + l15;
                const int off = row * 64 + ((ks * 32 + l4 * 8) ^ ((row & 7) << 3));
                af[mi] = *(const bf16x8*)&ldsA[off];
            }
            #pragma unroll
            for (int nj = 0; nj < 4; ++nj) {
                const int row = wn * 64 + nj * 16 + l15;
                const int off = row * 64 + ((ks * 32 + l4 * 8) ^ ((row & 7) << 3));
                bf[nj] = *(const bf16x8*)&ldsW[off];
            }
            #pragma unroll
            for (int mi = 0; mi < 4; ++mi)
                #pragma unroll
                for (int nj = 0; nj < 4; ++nj)
                    acc[mi][nj] = __builtin_amdgcn_mfma_f32_16x16x32_bf16(
                        bf[nj], af[mi], acc[mi][nj], 0, 0, 0);   // SWAPPED operands
        }
        __syncthreads();   // protect LDS before next stage overwrites
    }

    // ---- epilogue (transposed C layout): lane owns row m = ...+l15,
    //      cols n = n0b + nj*16 + l4*4 + {0..3} ----
    const int n0b = bt * 128 + wn * 64;
    float bj4[4][4];
    #pragma unroll
    for (int nj = 0; nj < 4; ++nj) {
        const int nb = n0b + nj * 16 + l4 * 4;
        if (nb + 3 < GV) {
            const float4 t = *(const float4*)&bias[nb];
            bj4[nj][0] = t.x; bj4[nj][1] = t.y; bj4[nj][2] = t.z; bj4[nj][3] = t.w;
        } else {
            #pragma unroll
            for (int r = 0; r < 4; ++r) bj4[nj][r] = (nb + r < GV) ? bias[nb + r] : 0.f;
        }
    }
    #pragma unroll
    for (int mi = 0; mi < 4; ++mi) {
        const int rowb = wm * 64 + mi * 16 + l15;
        const int m = bm * 128 + rowb;
        float v[4][4];
        float mx = -INFINITY;
        #pragma unroll
        for (int nj = 0; nj < 4; ++nj)
            #pragma unroll
            for (int r = 0; r < 4; ++r) {
                v[nj][r] = acc[mi][nj][r] + bj4[nj][r];
                if (n0b + nj * 16 + l4 * 4 + r < GV) mx = fmaxf(mx, v[nj][r]);
            }
        mx = fmaxf(mx, __shfl_xor(mx, 16));
        mx = fmaxf(mx, __shfl_xor(mx, 32));
        float se = 0.f;
        #pragma unroll
        for (int nj = 0; nj < 4; ++nj)
            #pragma unroll
            for (int r = 0; r < 4; ++r)
                if (n0b + nj * 16 + l4 * 4 + r < GV) se += __expf(v[nj][r] - mx);
        se += __shfl_xor(se, 16);
        se += __shfl_xor(se, 32);
        if (m < GM) {
            float* lrow = logits + (size_t)m * GV;
            #pragma unroll
            for (int nj = 0; nj < 4; ++nj) {
                const int nb = n0b + nj * 16 + l4 * 4;
                if (nb + 3 < GV) {
                    float4 st;
                    st.x = v[nj][0]; st.y = v[nj][1]; st.z = v[nj][2]; st.w = v[nj][3];
                    *(float4*)&lrow[nb] = st;
                } else {
                    #pragma unroll
                    for (int r = 0; r < 4; ++r)
                        if (nb + r < GV) lrow[nb + r] = v[nj][r];
                }
            }
        }
        if (l4 == 0) { sM[wn][rowb] = mx; sS[wn][rowb] = se; }
    }
    __syncthreads();
    if (tid < 128) {
        const int m = bm * 128 + tid;
        if (m < GM) {
            const float m0 = sM[0][tid], m1 = sM[1][tid];
            const float M = fmaxf(m0, m1);
            const float S = sS[0][tid] * __expf(m0 - M) + sS[1][tid] * __expf(m1 - M);
            pmax[(size_t)m * NT + bt] = M;
            psum[(size_t)m * NT + bt] = S;
        }
    }
}

// ---------------------------------------------------------------------------
// Kernel 4: merge per-tile (max,sum) -> per-row (max, 1/sum). 1 wave per row.
// ---------------------------------------------------------------------------
__global__ __launch_bounds__(64) void reduce_kernel(
    const float* __restrict__ pmax, const float* __restrict__ psum,
    float* __restrict__ rowM, float* __restrict__ rowInvS)
{
    const int m = blockIdx.x;
    const int lane = threadIdx.x;
    float M = -INFINITY, S = 0.f;
    for (int t = lane; t < NT; t += 64) {
        const float m2 = pmax[(size_t)m * NT + t];
        const float s2 = psum[(size_t)m * NT + t];
        const float nM = fmaxf(M, m2);
        S = S * expf(M - nM) + s2 * expf(m2 - nM);
        M = nM;
    }
    #pragma unroll
    for (int d = 1; d < 64; d <<= 1) {
        const float m2 = __shfl_xor(M, d);
        const float s2 = __shfl_xor(S, d);
        const float nM = fmaxf(M, m2);
        S = S * expf(M - nM) + s2 * expf(m2 - nM);
        M = nM;
    }
    if (lane == 0) { rowM[m] = M; rowInvS[m] = 1.f / S; }
}

// ---------------------------------------------------------------------------
// Kernel 5: probs = exp(logits - M) * invS. float4 grid-stride.
// ---------------------------------------------------------------------------
__global__ __launch_bounds__(256) void probs_kernel(
    const float* __restrict__ logits,
    const float* __restrict__ rowM, const float* __restrict__ rowInvS,
    float* __restrict__ probs)
{
    const float4* L4 = reinterpret_cast<const float4*>(logits);
    float4* P4 = reinterpret_cast<float4*>(probs);
    const int n4 = (int)(((long long)GM * GV) / 4);
    const int stride = gridDim.x * blockDim.x;
    for (int i = blockIdx.x * blockDim.x + threadIdx.x; i < n4; i += stride) {
        const float4 v = L4[i];
        const int base = i * 4;
        const int m0 = base / GV;
        const int m3 = (base + 3) / GV;
        float4 o;
        if (m0 == m3) {
            const float M = rowM[m0], Is = rowInvS[m0];
            o.x = __expf(v.x - M) * Is;
            o.y = __expf(v.y - M) * Is;
            o.z = __expf(v.z - M) * Is;
            o.w = __expf(v.w - M) * Is;
        } else {
            const int ma = base / GV, mb = (base + 1) / GV;
            const int mc = (base + 2) / GV, md = (base + 3) / GV;
            o.x = __expf(v.x - rowM[ma]) * rowInvS[ma];
            o.y = __expf(v.y - rowM[mb]) * rowInvS[mb];
            o.z = __expf(v.z - rowM[mc]) * rowInvS[mc];
            o.w = __expf(v.w - rowM[md]) * rowInvS[md];
        }
        P4[i] = o;
    }
}

// ---------------------------------------------------------------------------
extern "C" void kernel_launch(void* const* d_in, const int* in_sizes, int n_in,
                              void* d_out, int out_size, void* d_ws, size_t ws_size,
                              hipStream_t stream) {
    const int*   tok    = (const int*)d_in[0];
    const float* emb    = (const float*)d_in[1];
    const float* gate_k = (const float*)d_in[2];
    const float* gate_b = (const float*)d_in[3];
    const float* cand_k = (const float*)d_in[4];
    const float* cand_b = (const float*)d_in[5];
    const float* W      = (const float*)d_in[6];
    const float* bias   = (const float*)d_in[7];

    float* logits = (float*)d_out;
    float* probs  = logits + (size_t)GM * GV;

    float* ws = (float*)d_ws;
    float* gruout = ws;                                        // 640,000 f32
    unsigned short* Ap = (unsigned short*)(gruout + 640000);   // 40*4*8192 bf16
    unsigned short* Wp = Ap + (size_t)MT * 4 * 8192;           // 393*4*8192 bf16
    float* pmax    = (float*)(Wp + (size_t)NT * 4 * 8192);
    float* psum    = pmax + (size_t)GM * NT;
    float* rowM    = psum + (size_t)GM * NT;
    float* rowInvS = rowM + GM;

    gru_kernel<<<GB, 1024, 0, stream>>>(tok, emb, gate_k, gate_b, cand_k, cand_b, gruout);

    prep_kernel<<<(MT * 4 * 128 + 255) / 256, 256, 0, stream>>>(gruout, Ap, MT, GM);
    prep_kernel<<<(NT * 4 * 128 + 255) / 256, 256, 0, stream>>>(W, Wp, NT, GV);

    dim3 g2(MT, NT);   // m-tile fastest: W-tile L2/L3 locality
    mfma_logits_kernel<<<g2, 256, 0, stream>>>(Ap, Wp, bias, logits, pmax, psum);

    reduce_kernel<<<GM, 64, 0, stream>>>(pmax, psum, rowM, rowInvS);

    probs_kernel<<<4096, 256, 0, stream>>>(logits, rowM, rowInvS, probs);
}

// Round 11
// 1319.686 us; speedup vs baseline: 1.0328x; 1.0275x over previous
//
#include <hip/hip_runtime.h>
#include <hip/hip_bf16.h>
#include <math.h>

// Problem constants
#define GL 2
#define GH 128
#define GH2 256
#define GV 50257
#define GB 100
#define GT 50
#define GM 5000            // B*T rows
#define NT 393             // n tiles (128 wide): ceil(50257/128)
#define MT 40              // m tiles (128 tall): ceil(5000/128)

typedef __attribute__((ext_vector_type(4))) float f32x4;
typedef __attribute__((ext_vector_type(8))) short bf16x8;

// ---------------------------------------------------------------------------
// GRU, restructured (r11): hoist input-to-hidden matmuls out of the scan.
//   gather:  XB[m] = emb[tok[m]]
//   xpart:   GX = IN @ Kg_top (+0 bias), CX = IN @ Kc_top   (dense, all CUs)
//   scan:    per t: g = sig(GX[m] + h@Kg_bot + gb); c = tanh(CX[m] + (r*h)@Kc_bot + cb)
// Layer 0: IN = XB; layer 1: IN = H0 (layer-0 hidden states).
// Per-step weight traffic halves (768->384 KB/block); K halves; 4 barriers.
// ---------------------------------------------------------------------------
__global__ __launch_bounds__(256) void gather_kernel(
    const int* __restrict__ tok, const float* __restrict__ emb,
    float* __restrict__ xb)
{
    const int i = blockIdx.x * 256 + threadIdx.x;
    if (i < GM * 32) {
        const int m = i >> 5, k4 = (i & 31) * 4;
        *(float4*)&xb[(size_t)m * GH + k4] =
            *(const float4*)&emb[(size_t)tok[m] * GH + k4];
    }
}

__global__ __launch_bounds__(256) void xpart_kernel(
    const float* __restrict__ in,      // (GM,128)
    const float* __restrict__ gk,      // layer's gate_k, top 128 rows
    const float* __restrict__ ck,      // layer's cand_k, top 128 rows
    float* __restrict__ gx,            // (GM,256)
    float* __restrict__ cx)            // (GM,128)
{
    __shared__ float xs[16][128];
    __shared__ float cpart[2][16][128];
    const int m0 = blockIdx.x * 16;
    const int tid = threadIdx.x;
    #pragma unroll
    for (int p = 0; p < 8; ++p) {
        const int idx = p * 256 + tid;
        const int r = idx >> 7, kq = idx & 127;
        int m = m0 + r; if (m > GM - 1) m = GM - 1;
        xs[r][kq] = in[(size_t)m * GH + kq];
    }
    __syncthreads();
    {   // gate x-part: j = tid (256 cols)
        float acc[16];
        #pragma unroll
        for (int r = 0; r < 16; ++r) acc[r] = 0.f;
        for (int k = 0; k < GH; ++k) {
            const float w = gk[k * GH2 + tid];
            #pragma unroll
            for (int r = 0; r < 16; ++r) acc[r] += xs[r][k] * w;
        }
        #pragma unroll
        for (int r = 0; r < 16; ++r)
            if (m0 + r < GM) gx[(size_t)(m0 + r) * GH2 + tid] = acc[r];
    }
    {   // cand x-part: j = tid&127, K-half = tid>>7
        const int j = tid & 127, kh = tid >> 7;
        float acc[16];
        #pragma unroll
        for (int r = 0; r < 16; ++r) acc[r] = 0.f;
        for (int k = kh * 64; k < kh * 64 + 64; ++k) {
            const float w = ck[k * GH + j];
            #pragma unroll
            for (int r = 0; r < 16; ++r) acc[r] += xs[r][k] * w;
        }
        #pragma unroll
        for (int r = 0; r < 16; ++r) cpart[kh][r][j] = acc[r];
    }
    __syncthreads();
    for (int idx = tid; idx < 16 * 128; idx += 256) {
        const int r = idx >> 7, j = idx & 127;
        if (m0 + r < GM) cx[(size_t)(m0 + r) * GH + j] = cpart[0][r][j] + cpart[1][r][j];
    }
}

__global__ __launch_bounds__(1024) void scan_kernel(
    const float* __restrict__ gxp,   // (GM,256) gate x-part
    const float* __restrict__ cxp,   // (GM,128) cand x-part
    const float* __restrict__ gkb,   // gate_k bottom rows (h-part)
    const float* __restrict__ ckb,   // cand_k bottom rows (h-part)
    const float* __restrict__ gb,    // gate_b (256)
    const float* __restrict__ cb,    // cand_b (128)
    float* __restrict__ hout)        // (GM,128)
{
    const int b = blockIdx.x;
    const int tid = threadIdx.x;
    __shared__ float hs[GH];
    __shared__ float rh[GH];
    __shared__ float g[GH2];
    __shared__ float gpart[4][GH2];
    __shared__ float cpart[8][GH];
    if (tid < GH) hs[tid] = 0.f;
    __syncthreads();
    for (int t = 0; t < GT; ++t) {
        const int m = b * GT + t;
        {   // gate h-part: j = tid&255, 4-way K-split (32 rows each)
            const int j = tid & 255, t4 = tid >> 8;
            const float* col = gkb + (size_t)(t4 * 32) * GH2 + j;
            float acc = 0.f;
            #pragma unroll 8
            for (int i = 0; i < 32; ++i) acc += hs[t4 * 32 + i] * col[(size_t)i * GH2];
            gpart[t4][j] = acc;
        }
        __syncthreads();
        if (tid < GH2) {
            const float s = gxp[(size_t)m * GH2 + tid] + gpart[0][tid] + gpart[1][tid]
                          + gpart[2][tid] + gpart[3][tid] + gb[tid];
            g[tid] = 1.f / (1.f + expf(-s));
        }
        __syncthreads();
        if (tid < GH) rh[tid] = g[tid] * hs[tid];
        __syncthreads();
        {   // cand h-part: j = tid&127, 8-way K-split (16 rows each)
            const int j = tid & 127, t8 = tid >> 7;
            const float* col = ckb + (size_t)(t8 * 16) * GH + j;
            float acc = 0.f;
            #pragma unroll 8
            for (int i = 0; i < 16; ++i) acc += rh[t8 * 16 + i] * col[(size_t)i * GH];
            cpart[t8][j] = acc;
        }
        __syncthreads();
        if (tid < GH) {
            float cs = cxp[(size_t)m * GH + tid] + cb[tid];
            #pragma unroll
            for (int p = 0; p < 8; ++p) cs += cpart[p][tid];
            const float c = tanhf(cs);
            const float u = g[GH + tid];
            const float hn = u * hs[tid] + (1.f - u) * c;
            hs[tid] = hn;
            hout[(size_t)m * GH + tid] = hn;
        }
        __syncthreads();
    }
}

// ---------------------------------------------------------------------------
// bf16 split helpers
// ---------------------------------------------------------------------------
__device__ __forceinline__ unsigned short f2bf(float x) {
    union { float f; unsigned u; } c; c.f = x;
    unsigned r = c.u + 0x7FFFu + ((c.u >> 16) & 1u);   // RNE
    return (unsigned short)(r >> 16);
}
__device__ __forceinline__ float bf2f(unsigned short b) {
    union { unsigned u; float f; } c; c.u = ((unsigned)b) << 16; return c.f;
}

// ---------------------------------------------------------------------------
// Kernel 2: prep — fp32 (rows x 128) -> staged XOR-swizzled bf16 chunks.
// chunk 0: hi(k0..63)  1: hi(k64..127)  2: lo(k0..63)  3: lo(k64..127)
// (r,k) stored at r*64 + (k ^ ((r&7)<<3)): linear global_load_lds then yields
// a bank-conflict-free swizzled LDS image (swizzle source + read, rule #21).
// ---------------------------------------------------------------------------
__global__ __launch_bounds__(256) void prep_kernel(
    const float* __restrict__ src, unsigned short* __restrict__ dst,
    int ntiles, int nrows)
{
    const int idx = blockIdx.x * 256 + threadIdx.x;
    if (idx >= ntiles * 4 * 128) return;
    const int r    = idx & 127;
    const int c    = idx >> 7;
    const int cs   = c & 3;
    const int tile = c >> 2;
    int row = tile * 128 + r; if (row > nrows - 1) row = nrows - 1;
    const float* s = src + (size_t)row * GH + (cs & 1) * 64;
    unsigned short* d = dst + (size_t)c * 8192 + r * 64;
    const bool lo = (cs >= 2);
    const int rx = r & 7;

    #pragma unroll
    for (int gq = 0; gq < 8; ++gq) {
        float x[8];
        *(float4*)(x)     = *(const float4*)(s + gq * 8);
        *(float4*)(x + 4) = *(const float4*)(s + gq * 8 + 4);
        unsigned u[4];
        #pragma unroll
        for (int q = 0; q < 4; ++q) {
            const float a0 = x[q * 2], a1 = x[q * 2 + 1];
            const unsigned short hi0 = f2bf(a0), hi1 = f2bf(a1);
            unsigned short h0, h1;
            if (lo) { h0 = f2bf(a0 - bf2f(hi0)); h1 = f2bf(a1 - bf2f(hi1)); }
            else    { h0 = hi0; h1 = hi1; }
            u[q] = (unsigned)h0 | ((unsigned)h1 << 16);
        }
        *(uint4*)(d + (size_t)((gq ^ rx) * 8)) = *(const uint4*)u;
    }
}

// ---------------------------------------------------------------------------
// Kernel 3: MFMA logits GEMM (r10 version, unchanged): K=384 bf16
// (hi*hi + hi*lo + lo*hi), 128x128 tile, 4 waves, single-buffered,
// min-staging walk, m-fastest grid, operand-swapped MFMA (row-major C:
// dwordx4 stores, 2 shfl per row-group).
//   step:     0        1        2        3        4        5
//   prod:  Ah0*Wl0  Ah0*Wh0  Al0*Wh0  Ah1*Wl1  Ah1*Wh1  Al1*Wh1
//   stage:  A0,W2     W0       A2      A1,W3     W1       A3
// ---------------------------------------------------------------------------
__global__ __launch_bounds__(256) void mfma_logits_kernel(
    const unsigned short* __restrict__ Ap, const unsigned short* __restrict__ Wp,
    const float* __restrict__ bias,
    float* __restrict__ logits, float* __restrict__ pmax, float* __restrict__ psum)
{
    __shared__ unsigned short ldsA[8192];
    __shared__ unsigned short ldsW[8192];
    __shared__ float sM[2][128];
    __shared__ float sS[2][128];

    const int bm  = blockIdx.x;     // m tile (fastest -> W-tile L2 locality)
    const int bt  = blockIdx.y;     // n tile
    const int tid = threadIdx.x;
    const int wid  = tid >> 6;
    const int lane = tid & 63;
    const int wm = wid >> 1, wn = wid & 1;
    const int l15 = lane & 15, l4 = lane >> 4;

    // minimum-staging walk (see header comment)
    constexpr int amap[6] = {0, 0, 2, 1, 1, 3};
    constexpr int astg[6] = {1, 0, 1, 1, 0, 1};
    constexpr int wmap[6] = {2, 0, 0, 3, 1, 1};
    constexpr int wstg[6] = {1, 1, 0, 1, 1, 0};

    f32x4 acc[4][4];
    #pragma unroll
    for (int i = 0; i < 4; ++i)
        #pragma unroll
        for (int j = 0; j < 4; ++j) acc[i][j] = (f32x4){0.f, 0.f, 0.f, 0.f};

    #pragma unroll
    for (int s = 0; s < 6; ++s) {
        if (astg[s]) {
            const unsigned short* ga = Ap + (size_t)(bm * 4 + amap[s]) * 8192 + wid * 2048 + lane * 8;
            #pragma unroll
            for (int i = 0; i < 4; ++i)
                __builtin_amdgcn_global_load_lds(
                    (const __attribute__((address_space(1))) void*)(ga + i * 512),
                    (__attribute__((address_space(3))) void*)(&ldsA[wid * 2048 + i * 512]), 16, 0, 0);
        }
        if (wstg[s]) {
            const unsigned short* gw = Wp + (size_t)(bt * 4 + wmap[s]) * 8192 + wid * 2048 + lane * 8;
            #pragma unroll
            for (int i = 0; i < 4; ++i)
                __builtin_amdgcn_global_load_lds(
                    (const __attribute__((address_space(1))) void*)(gw + i * 512),
                    (__attribute__((address_space(3))) void*)(&ldsW[wid * 2048 + i * 512]), 16, 0, 0);
        }
        __syncthreads();   // drains vmcnt before barrier -> LDS image complete

        #pragma unroll
        for (int ks = 0; ks < 2; ++ks) {
            bf16x8 af[4], bf[4];
            #pragma unroll
            for (int mi = 0; mi < 4; ++mi) {
                const int row = wm * 64 + mi * 16 + l15;
                const int off = row * 64 + ((ks * 32 + l4 * 8) ^ ((row & 7) << 3));
                af[mi] = *(const bf16x8*)&ldsA[off];
            }
            #pragma unroll
            for (int nj = 0; nj < 4; ++nj) {
                const int row = wn * 64 + nj * 16 + l15;
                const int off = row * 64 + ((ks * 32 + l4 * 8) ^ ((row & 7) << 3));
                bf[nj] = *(const bf16x8*)&ldsW[off];
            }
            #pragma unroll
            for (int mi = 0; mi < 4; ++mi)
                #pragma unroll
                for (int nj = 0; nj < 4; ++nj)
                    acc[mi][nj] = __builtin_amdgcn_mfma_f32_16x16x32_bf16(
                        bf[nj], af[mi], acc[mi][nj], 0, 0, 0);   // SWAPPED operands
        }
        __syncthreads();   // protect LDS before next stage overwrites
    }

    // ---- epilogue (transposed C layout): lane owns row m = ...+l15,
    //      cols n = n0b + nj*16 + l4*4 + {0..3} ----
    const int n0b = bt * 128 + wn * 64;
    float bj4[4][4];
    #pragma unroll
    for (int nj = 0; nj < 4; ++nj) {
        const int nb = n0b + nj * 16 + l4 * 4;
        if (nb + 3 < GV) {
            const float4 t = *(const float4*)&bias[nb];
            bj4[nj][0] = t.x; bj4[nj][1] = t.y; bj4[nj][2] = t.z; bj4[nj][3] = t.w;
        } else {
            #pragma unroll
            for (int r = 0; r < 4; ++r) bj4[nj][r] = (nb + r < GV) ? bias[nb + r] : 0.f;
        }
    }
    #pragma unroll
    for (int mi = 0; mi < 4; ++mi) {
        const int rowb = wm * 64 + mi * 16 + l15;
        const int m = bm * 128 + rowb;
        float v[4][4];
        float mx = -INFINITY;
        #pragma unroll
        for (int nj = 0; nj < 4; ++nj)
            #pragma unroll
            for (int r = 0; r < 4; ++r) {
                v[nj][r] = acc[mi][nj][r] + bj4[nj][r];
                if (n0b + nj * 16 + l4 * 4 + r < GV) mx = fmaxf(mx, v[nj][r]);
            }
        mx = fmaxf(mx, __shfl_xor(mx, 16));
        mx = fmaxf(mx, __shfl_xor(mx, 32));
        float se = 0.f;
        #pragma unroll
        for (int nj = 0; nj < 4; ++nj)
            #pragma unroll
            for (int r = 0; r < 4; ++r)
                if (n0b + nj * 16 + l4 * 4 + r < GV) se += __expf(v[nj][r] - mx);
        se += __shfl_xor(se, 16);
        se += __shfl_xor(se, 32);
        if (m < GM) {
            float* lrow = logits + (size_t)m * GV;
            #pragma unroll
            for (int nj = 0; nj < 4; ++nj) {
                const int nb = n0b + nj * 16 + l4 * 4;
                if (nb + 3 < GV) {
                    float4 st;
                    st.x = v[nj][0]; st.y = v[nj][1]; st.z = v[nj][2]; st.w = v[nj][3];
                    *(float4*)&lrow[nb] = st;
                } else {
                    #pragma unroll
                    for (int r = 0; r < 4; ++r)
                        if (nb + r < GV) lrow[nb + r] = v[nj][r];
                }
            }
        }
        if (l4 == 0) { sM[wn][rowb] = mx; sS[wn][rowb] = se; }
    }
    __syncthreads();
    if (tid < 128) {
        const int m = bm * 128 + tid;
        if (m < GM) {
            const float m0 = sM[0][tid], m1 = sM[1][tid];
            const float M = fmaxf(m0, m1);
            const float S = sS[0][tid] * __expf(m0 - M) + sS[1][tid] * __expf(m1 - M);
            pmax[(size_t)m * NT + bt] = M;
            psum[(size_t)m * NT + bt] = S;
        }
    }
}

// ---------------------------------------------------------------------------
// Kernel 4: merge per-tile (max,sum) -> per-row (max, 1/sum). 1 wave per row.
// ---------------------------------------------------------------------------
__global__ __launch_bounds__(64) void reduce_kernel(
    const float* __restrict__ pmax, const float* __restrict__ psum,
    float* __restrict__ rowM, float* __restrict__ rowInvS)
{
    const int m = blockIdx.x;
    const int lane = threadIdx.x;
    float M = -INFINITY, S = 0.f;
    for (int t = lane; t < NT; t += 64) {
        const float m2 = pmax[(size_t)m * NT + t];
        const float s2 = psum[(size_t)m * NT + t];
        const float nM = fmaxf(M, m2);
        S = S * expf(M - nM) + s2 * expf(m2 - nM);
        M = nM;
    }
    #pragma unroll
    for (int d = 1; d < 64; d <<= 1) {
        const float m2 = __shfl_xor(M, d);
        const float s2 = __shfl_xor(S, d);
        const float nM = fmaxf(M, m2);
        S = S * expf(M - nM) + s2 * expf(m2 - nM);
        M = nM;
    }
    if (lane == 0) { rowM[m] = M; rowInvS[m] = 1.f / S; }
}

// ---------------------------------------------------------------------------
// Kernel 5: probs = exp(logits - M) * invS. float4 grid-stride.
// ---------------------------------------------------------------------------
__global__ __launch_bounds__(256) void probs_kernel(
    const float* __restrict__ logits,
    const float* __restrict__ rowM, const float* __restrict__ rowInvS,
    float* __restrict__ probs)
{
    const float4* L4 = reinterpret_cast<const float4*>(logits);
    float4* P4 = reinterpret_cast<float4*>(probs);
    const int n4 = (int)(((long long)GM * GV) / 4);
    const int stride = gridDim.x * blockDim.x;
    for (int i = blockIdx.x * blockDim.x + threadIdx.x; i < n4; i += stride) {
        const float4 v = L4[i];
        const int base = i * 4;
        const int m0 = base / GV;
        const int m3 = (base + 3) / GV;
        float4 o;
        if (m0 == m3) {
            const float M = rowM[m0], Is = rowInvS[m0];
            o.x = __expf(v.x - M) * Is;
            o.y = __expf(v.y - M) * Is;
            o.z = __expf(v.z - M) * Is;
            o.w = __expf(v.w - M) * Is;
        } else {
            const int ma = base / GV, mb = (base + 1) / GV;
            const int mc = (base + 2) / GV, md = (base + 3) / GV;
            o.x = __expf(v.x - rowM[ma]) * rowInvS[ma];
            o.y = __expf(v.y - rowM[mb]) * rowInvS[mb];
            o.z = __expf(v.z - rowM[mc]) * rowInvS[mc];
            o.w = __expf(v.w - rowM[md]) * rowInvS[md];
        }
        P4[i] = o;
    }
}

// ---------------------------------------------------------------------------
extern "C" void kernel_launch(void* const* d_in, const int* in_sizes, int n_in,
                              void* d_out, int out_size, void* d_ws, size_t ws_size,
                              hipStream_t stream) {
    const int*   tok    = (const int*)d_in[0];
    const float* emb    = (const float*)d_in[1];
    const float* gate_k = (const float*)d_in[2];
    const float* gate_b = (const float*)d_in[3];
    const float* cand_k = (const float*)d_in[4];
    const float* cand_b = (const float*)d_in[5];
    const float* W      = (const float*)d_in[6];
    const float* bias   = (const float*)d_in[7];

    float* logits = (float*)d_out;
    float* probs  = logits + (size_t)GM * GV;

    float* ws = (float*)d_ws;
    float* gruout = ws;                                        // 640,000 f32
    unsigned short* Ap = (unsigned short*)(gruout + 640000);   // 40*4*8192 bf16
    unsigned short* Wp = Ap + (size_t)MT * 4 * 8192;           // 393*4*8192 bf16
    float* pmax    = (float*)(Wp + (size_t)NT * 4 * 8192);
    float* psum    = pmax + (size_t)GM * NT;
    float* rowM    = psum + (size_t)GM * NT;
    float* rowInvS = rowM + GM;

    // GRU scratch OVERLAYS the pmax region (2.56M floats < 3.93M; pmax is
    // written only by the later GEMM, stream-ordered after the GRU phase).
    float* XBH0 = pmax;                 // 640,000 (XB, then H0 after P0 consumed it)
    float* GX   = pmax + 640000;        // 1,280,000
    float* CX   = pmax + 1920000;       // 640,000

    // ---- GRU phase ----
    gather_kernel<<<(GM * 32 + 255) / 256, 256, 0, stream>>>(tok, emb, XBH0);
    xpart_kernel<<<(GM + 15) / 16, 256, 0, stream>>>(XBH0, gate_k, cand_k, GX, CX);
    scan_kernel<<<GB, 1024, 0, stream>>>(GX, CX,
        gate_k + 128 * GH2, cand_k + 128 * GH, gate_b, cand_b, XBH0 /* = H0 */);
    xpart_kernel<<<(GM + 15) / 16, 256, 0, stream>>>(XBH0,
        gate_k + GH2 * GH2, cand_k + GH2 * GH, GX, CX);
    scan_kernel<<<GB, 1024, 0, stream>>>(GX, CX,
        gate_k + GH2 * GH2 + 128 * GH2, cand_k + GH2 * GH + 128 * GH,
        gate_b + GH2, cand_b + GH, gruout);

    // ---- logits + softmax phase (unchanged from r10) ----
    prep_kernel<<<(MT * 4 * 128 + 255) / 256, 256, 0, stream>>>(gruout, Ap, MT, GM);
    prep_kernel<<<(NT * 4 * 128 + 255) / 256, 256, 0, stream>>>(W, Wp, NT, GV);

    dim3 g2(MT, NT);   // m-tile fastest: W-tile L2/L3 locality
    mfma_logits_kernel<<<g2, 256, 0, stream>>>(Ap, Wp, bias, logits, pmax, psum);

    reduce_kernel<<<GM, 64, 0, stream>>>(pmax, psum, rowM, rowInvS);

    probs_kernel<<<4096, 256, 0, stream>>>(logits, rowM, rowInvS, probs);
}

// Round 12
// 1186.960 us; speedup vs baseline: 1.1483x; 1.1118x over previous
//
#include <hip/hip_runtime.h>
#include <hip/hip_bf16.h>
#include <math.h>

// Problem constants
#define GL 2
#define GH 128
#define GH2 256
#define GV 50257
#define GB 100
#define GT 50
#define GM 5000            // B*T rows
#define NT 393             // n tiles (128 wide): ceil(50257/128)
#define MT 40              // m tiles (128 tall): ceil(5000/128)

typedef __attribute__((ext_vector_type(4))) float f32x4;
typedef __attribute__((ext_vector_type(8))) short bf16x8;

// ---------------------------------------------------------------------------
// GRU (r12): hoisted x-parts (r11) + PERSISTENT-REGISTER scan weights.
// h-part weights (gate 128x256 + cand 128x128 = 48K floats) are loaded ONCE
// into VGPRs (48 floats/thread @ 1024 threads), eliminating the 384 KB/step
// L2 weight re-stream that dominated the r11 scan. Static-index unrolled
// register arrays (rule #20). Math bitwise-identical to r11.
// ---------------------------------------------------------------------------
__global__ __launch_bounds__(256) void gather_kernel(
    const int* __restrict__ tok, const float* __restrict__ emb,
    float* __restrict__ xb)
{
    const int i = blockIdx.x * 256 + threadIdx.x;
    if (i < GM * 32) {
        const int m = i >> 5, k4 = (i & 31) * 4;
        *(float4*)&xb[(size_t)m * GH + k4] =
            *(const float4*)&emb[(size_t)tok[m] * GH + k4];
    }
}

__global__ __launch_bounds__(256) void xpart_kernel(
    const float* __restrict__ in,      // (GM,128)
    const float* __restrict__ gk,      // layer's gate_k, top 128 rows
    const float* __restrict__ ck,      // layer's cand_k, top 128 rows
    float* __restrict__ gx,            // (GM,256)
    float* __restrict__ cx)            // (GM,128)
{
    __shared__ float xs[16][128];
    __shared__ float cpart[2][16][128];
    const int m0 = blockIdx.x * 16;
    const int tid = threadIdx.x;
    #pragma unroll
    for (int p = 0; p < 8; ++p) {
        const int idx = p * 256 + tid;
        const int r = idx >> 7, kq = idx & 127;
        int m = m0 + r; if (m > GM - 1) m = GM - 1;
        xs[r][kq] = in[(size_t)m * GH + kq];
    }
    __syncthreads();
    {   // gate x-part: j = tid (256 cols)
        float acc[16];
        #pragma unroll
        for (int r = 0; r < 16; ++r) acc[r] = 0.f;
        for (int k = 0; k < GH; ++k) {
            const float w = gk[k * GH2 + tid];
            #pragma unroll
            for (int r = 0; r < 16; ++r) acc[r] += xs[r][k] * w;
        }
        #pragma unroll
        for (int r = 0; r < 16; ++r)
            if (m0 + r < GM) gx[(size_t)(m0 + r) * GH2 + tid] = acc[r];
    }
    {   // cand x-part: j = tid&127, K-half = tid>>7
        const int j = tid & 127, kh = tid >> 7;
        float acc[16];
        #pragma unroll
        for (int r = 0; r < 16; ++r) acc[r] = 0.f;
        for (int k = kh * 64; k < kh * 64 + 64; ++k) {
            const float w = ck[k * GH + j];
            #pragma unroll
            for (int r = 0; r < 16; ++r) acc[r] += xs[r][k] * w;
        }
        #pragma unroll
        for (int r = 0; r < 16; ++r) cpart[kh][r][j] = acc[r];
    }
    __syncthreads();
    for (int idx = tid; idx < 16 * 128; idx += 256) {
        const int r = idx >> 7, j = idx & 127;
        if (m0 + r < GM) cx[(size_t)(m0 + r) * GH + j] = cpart[0][r][j] + cpart[1][r][j];
    }
}

__global__ __launch_bounds__(1024) void scan_kernel(
    const float* __restrict__ gxp,   // (GM,256) gate x-part
    const float* __restrict__ cxp,   // (GM,128) cand x-part
    const float* __restrict__ gkb,   // gate_k bottom rows (h-part)
    const float* __restrict__ ckb,   // cand_k bottom rows (h-part)
    const float* __restrict__ gb,    // gate_b (256)
    const float* __restrict__ cb,    // cand_b (128)
    float* __restrict__ hout)        // (GM,128)
{
    const int b = blockIdx.x;
    const int tid = threadIdx.x;
    const int jg = tid & 255, t4 = tid >> 8;   // gate mapping
    const int jc = tid & 127, t8 = tid >> 7;   // cand mapping

    // ---- persistent weights: loaded once, live in VGPRs across the scan ----
    float wg[32], wc[16];
    #pragma unroll
    for (int i = 0; i < 32; ++i) wg[i] = gkb[(size_t)(t4 * 32 + i) * GH2 + jg];
    #pragma unroll
    for (int i = 0; i < 16; ++i) wc[i] = ckb[(size_t)(t8 * 16 + i) * GH + jc];

    __shared__ float hs[GH];
    __shared__ float rh[GH];
    __shared__ float g[GH2];
    __shared__ float gpart[4][GH2];
    __shared__ float cpart[8][GH];
    if (tid < GH) hs[tid] = 0.f;
    __syncthreads();

    for (int t = 0; t < GT; ++t) {
        const int m = b * GT + t;
        {   // gate h-part: 4-way K-split, weights from registers
            float acc = 0.f;
            #pragma unroll
            for (int i = 0; i < 32; ++i) acc += hs[t4 * 32 + i] * wg[i];
            gpart[t4][jg] = acc;
        }
        __syncthreads();
        if (tid < GH2) {
            const float s = gxp[(size_t)m * GH2 + tid] + gpart[0][tid] + gpart[1][tid]
                          + gpart[2][tid] + gpart[3][tid] + gb[tid];
            g[tid] = 1.f / (1.f + expf(-s));
        }
        __syncthreads();
        if (tid < GH) rh[tid] = g[tid] * hs[tid];
        __syncthreads();
        {   // cand h-part: 8-way K-split, weights from registers
            float acc = 0.f;
            #pragma unroll
            for (int i = 0; i < 16; ++i) acc += rh[t8 * 16 + i] * wc[i];
            cpart[t8][jc] = acc;
        }
        __syncthreads();
        if (tid < GH) {
            float cs = cxp[(size_t)m * GH + tid] + cb[tid];
            #pragma unroll
            for (int p = 0; p < 8; ++p) cs += cpart[p][tid];
            const float c = tanhf(cs);
            const float u = g[GH + tid];
            const float hn = u * hs[tid] + (1.f - u) * c;
            hs[tid] = hn;
            hout[(size_t)m * GH + tid] = hn;
        }
        __syncthreads();
    }
}

// ---------------------------------------------------------------------------
// bf16 split helpers
// ---------------------------------------------------------------------------
__device__ __forceinline__ unsigned short f2bf(float x) {
    union { float f; unsigned u; } c; c.f = x;
    unsigned r = c.u + 0x7FFFu + ((c.u >> 16) & 1u);   // RNE
    return (unsigned short)(r >> 16);
}
__device__ __forceinline__ float bf2f(unsigned short b) {
    union { unsigned u; float f; } c; c.u = ((unsigned)b) << 16; return c.f;
}

// ---------------------------------------------------------------------------
// Kernel 2: prep — fp32 (rows x 128) -> staged XOR-swizzled bf16 chunks.
// chunk 0: hi(k0..63)  1: hi(k64..127)  2: lo(k0..63)  3: lo(k64..127)
// (r,k) stored at r*64 + (k ^ ((r&7)<<3)): linear global_load_lds then yields
// a bank-conflict-free swizzled LDS image (swizzle source + read, rule #21).
// ---------------------------------------------------------------------------
__global__ __launch_bounds__(256) void prep_kernel(
    const float* __restrict__ src, unsigned short* __restrict__ dst,
    int ntiles, int nrows)
{
    const int idx = blockIdx.x * 256 + threadIdx.x;
    if (idx >= ntiles * 4 * 128) return;
    const int r    = idx & 127;
    const int c    = idx >> 7;
    const int cs   = c & 3;
    const int tile = c >> 2;
    int row = tile * 128 + r; if (row > nrows - 1) row = nrows - 1;
    const float* s = src + (size_t)row * GH + (cs & 1) * 64;
    unsigned short* d = dst + (size_t)c * 8192 + r * 64;
    const bool lo = (cs >= 2);
    const int rx = r & 7;

    #pragma unroll
    for (int gq = 0; gq < 8; ++gq) {
        float x[8];
        *(float4*)(x)     = *(const float4*)(s + gq * 8);
        *(float4*)(x + 4) = *(const float4*)(s + gq * 8 + 4);
        unsigned u[4];
        #pragma unroll
        for (int q = 0; q < 4; ++q) {
            const float a0 = x[q * 2], a1 = x[q * 2 + 1];
            const unsigned short hi0 = f2bf(a0), hi1 = f2bf(a1);
            unsigned short h0, h1;
            if (lo) { h0 = f2bf(a0 - bf2f(hi0)); h1 = f2bf(a1 - bf2f(hi1)); }
            else    { h0 = hi0; h1 = hi1; }
            u[q] = (unsigned)h0 | ((unsigned)h1 << 16);
        }
        *(uint4*)(d + (size_t)((gq ^ rx) * 8)) = *(const uint4*)u;
    }
}

// ---------------------------------------------------------------------------
// Kernel 3: MFMA logits GEMM (r10 version, unchanged): K=384 bf16
// (hi*hi + hi*lo + lo*hi), 128x128 tile, 4 waves, single-buffered,
// min-staging walk, m-fastest grid, operand-swapped MFMA (row-major C:
// dwordx4 stores, 2 shfl per row-group).
//   step:     0        1        2        3        4        5
//   prod:  Ah0*Wl0  Ah0*Wh0  Al0*Wh0  Ah1*Wl1  Ah1*Wh1  Al1*Wh1
//   stage:  A0,W2     W0       A2      A1,W3     W1       A3
// ---------------------------------------------------------------------------
__global__ __launch_bounds__(256) void mfma_logits_kernel(
    const unsigned short* __restrict__ Ap, const unsigned short* __restrict__ Wp,
    const float* __restrict__ bias,
    float* __restrict__ logits, float* __restrict__ pmax, float* __restrict__ psum)
{
    __shared__ unsigned short ldsA[8192];
    __shared__ unsigned short ldsW[8192];
    __shared__ float sM[2][128];
    __shared__ float sS[2][128];

    const int bm  = blockIdx.x;     // m tile (fastest -> W-tile L2 locality)
    const int bt  = blockIdx.y;     // n tile
    const int tid = threadIdx.x;
    const int wid  = tid >> 6;
    const int lane = tid & 63;
    const int wm = wid >> 1, wn = wid & 1;
    const int l15 = lane & 15, l4 = lane >> 4;

    // minimum-staging walk (see header comment)
    constexpr int amap[6] = {0, 0, 2, 1, 1, 3};
    constexpr int astg[6] = {1, 0, 1, 1, 0, 1};
    constexpr int wmap[6] = {2, 0, 0, 3, 1, 1};
    constexpr int wstg[6] = {1, 1, 0, 1, 1, 0};

    f32x4 acc[4][4];
    #pragma unroll
    for (int i = 0; i < 4; ++i)
        #pragma unroll
        for (int j = 0; j < 4; ++j) acc[i][j] = (f32x4){0.f, 0.f, 0.f, 0.f};

    #pragma unroll
    for (int s = 0; s < 6; ++s) {
        if (astg[s]) {
            const unsigned short* ga = Ap + (size_t)(bm * 4 + amap[s]) * 8192 + wid * 2048 + lane * 8;
            #pragma unroll
            for (int i = 0; i < 4; ++i)
                __builtin_amdgcn_global_load_lds(
                    (const __attribute__((address_space(1))) void*)(ga + i * 512),
                    (__attribute__((address_space(3))) void*)(&ldsA[wid * 2048 + i * 512]), 16, 0, 0);
        }
        if (wstg[s]) {
            const unsigned short* gw = Wp + (size_t)(bt * 4 + wmap[s]) * 8192 + wid * 2048 + lane * 8;
            #pragma unroll
            for (int i = 0; i < 4; ++i)
                __builtin_amdgcn_global_load_lds(
                    (const __attribute__((address_space(1))) void*)(gw + i * 512),
                    (__attribute__((address_space(3))) void*)(&ldsW[wid * 2048 + i * 512]), 16, 0, 0);
        }
        __syncthreads();   // drains vmcnt before barrier -> LDS image complete

        #pragma unroll
        for (int ks = 0; ks < 2; ++ks) {
            bf16x8 af[4], bf[4];
            #pragma unroll
            for (int mi = 0; mi < 4; ++mi) {
                const int row = wm * 64 + mi * 16 + l15;
                const int off = row * 64 + ((ks * 32 + l4 * 8) ^ ((row & 7) << 3));
                af[mi] = *(const bf16x8*)&ldsA[off];
            }
            #pragma unroll
            for (int nj = 0; nj < 4; ++nj) {
                const int row = wn * 64 + nj * 16 + l15;
                const int off = row * 64 + ((ks * 32 + l4 * 8) ^ ((row & 7) << 3));
                bf[nj] = *(const bf16x8*)&ldsW[off];
            }
            #pragma unroll
            for (int mi = 0; mi < 4; ++mi)
                #pragma unroll
                for (int nj = 0; nj < 4; ++nj)
                    acc[mi][nj] = __builtin_amdgcn_mfma_f32_16x16x32_bf16(
                        bf[nj], af[mi], acc[mi][nj], 0, 0, 0);   // SWAPPED operands
        }
        __syncthreads();   // protect LDS before next stage overwrites
    }

    // ---- epilogue (transposed C layout): lane owns row m = ...+l15,
    //      cols n = n0b + nj*16 + l4*4 + {0..3} ----
    const int n0b = bt * 128 + wn * 64;
    float bj4[4][4];
    #pragma unroll
    for (int nj = 0; nj < 4; ++nj) {
        const int nb = n0b + nj * 16 + l4 * 4;
        if (nb + 3 < GV) {
            const float4 t = *(const float4*)&bias[nb];
            bj4[nj][0] = t.x; bj4[nj][1] = t.y; bj4[nj][2] = t.z; bj4[nj][3] = t.w;
        } else {
            #pragma unroll
            for (int r = 0; r < 4; ++r) bj4[nj][r] = (nb + r < GV) ? bias[nb + r] : 0.f;
        }
    }
    #pragma unroll
    for (int mi = 0; mi < 4; ++mi) {
        const int rowb = wm * 64 + mi * 16 + l15;
        const int m = bm * 128 + rowb;
        float v[4][4];
        float mx = -INFINITY;
        #pragma unroll
        for (int nj = 0; nj < 4; ++nj)
            #pragma unroll
            for (int r = 0; r < 4; ++r) {
                v[nj][r] = acc[mi][nj][r] + bj4[nj][r];
                if (n0b + nj * 16 + l4 * 4 + r < GV) mx = fmaxf(mx, v[nj][r]);
            }
        mx = fmaxf(mx, __shfl_xor(mx, 16));
        mx = fmaxf(mx, __shfl_xor(mx, 32));
        float se = 0.f;
        #pragma unroll
        for (int nj = 0; nj < 4; ++nj)
            #pragma unroll
            for (int r = 0; r < 4; ++r)
                if (n0b + nj * 16 + l4 * 4 + r < GV) se += __expf(v[nj][r] - mx);
        se += __shfl_xor(se, 16);
        se += __shfl_xor(se, 32);
        if (m < GM) {
            float* lrow = logits + (size_t)m * GV;
            #pragma unroll
            for (int nj = 0; nj < 4; ++nj) {
                const int nb = n0b + nj * 16 + l4 * 4;
                if (nb + 3 < GV) {
                    float4 st;
                    st.x = v[nj][0]; st.y = v[nj][1]; st.z = v[nj][2]; st.w = v[nj][3];
                    *(float4*)&lrow[nb] = st;
                } else {
                    #pragma unroll
                    for (int r = 0; r < 4; ++r)
                        if (nb + r < GV) lrow[nb + r] = v[nj][r];
                }
            }
        }
        if (l4 == 0) { sM[wn][rowb] = mx; sS[wn][rowb] = se; }
    }
    __syncthreads();
    if (tid < 128) {
        const int m = bm * 128 + tid;
        if (m < GM) {
            const float m0 = sM[0][tid], m1 = sM[1][tid];
            const float M = fmaxf(m0, m1);
            const float S = sS[0][tid] * __expf(m0 - M) + sS[1][tid] * __expf(m1 - M);
            pmax[(size_t)m * NT + bt] = M;
            psum[(size_t)m * NT + bt] = S;
        }
    }
}

// ---------------------------------------------------------------------------
// Kernel 4: merge per-tile (max,sum) -> per-row (max, 1/sum). 1 wave per row.
// ---------------------------------------------------------------------------
__global__ __launch_bounds__(64) void reduce_kernel(
    const float* __restrict__ pmax, const float* __restrict__ psum,
    float* __restrict__ rowM, float* __restrict__ rowInvS)
{
    const int m = blockIdx.x;
    const int lane = threadIdx.x;
    float M = -INFINITY, S = 0.f;
    for (int t = lane; t < NT; t += 64) {
        const float m2 = pmax[(size_t)m * NT + t];
        const float s2 = psum[(size_t)m * NT + t];
        const float nM = fmaxf(M, m2);
        S = S * expf(M - nM) + s2 * expf(m2 - nM);
        M = nM;
    }
    #pragma unroll
    for (int d = 1; d < 64; d <<= 1) {
        const float m2 = __shfl_xor(M, d);
        const float s2 = __shfl_xor(S, d);
        const float nM = fmaxf(M, m2);
        S = S * expf(M - nM) + s2 * expf(m2 - nM);
        M = nM;
    }
    if (lane == 0) { rowM[m] = M; rowInvS[m] = 1.f / S; }
}

// ---------------------------------------------------------------------------
// Kernel 5: probs = exp(logits - M) * invS. float4 grid-stride.
// ---------------------------------------------------------------------------
__global__ __launch_bounds__(256) void probs_kernel(
    const float* __restrict__ logits,
    const float* __restrict__ rowM, const float* __restrict__ rowInvS,
    float* __restrict__ probs)
{
    const float4* L4 = reinterpret_cast<const float4*>(logits);
    float4* P4 = reinterpret_cast<float4*>(probs);
    const int n4 = (int)(((long long)GM * GV) / 4);
    const int stride = gridDim.x * blockDim.x;
    for (int i = blockIdx.x * blockDim.x + threadIdx.x; i < n4; i += stride) {
        const float4 v = L4[i];
        const int base = i * 4;
        const int m0 = base / GV;
        const int m3 = (base + 3) / GV;
        float4 o;
        if (m0 == m3) {
            const float M = rowM[m0], Is = rowInvS[m0];
            o.x = __expf(v.x - M) * Is;
            o.y = __expf(v.y - M) * Is;
            o.z = __expf(v.z - M) * Is;
            o.w = __expf(v.w - M) * Is;
        } else {
            const int ma = base / GV, mb = (base + 1) / GV;
            const int mc = (base + 2) / GV, md = (base + 3) / GV;
            o.x = __expf(v.x - rowM[ma]) * rowInvS[ma];
            o.y = __expf(v.y - rowM[mb]) * rowInvS[mb];
            o.z = __expf(v.z - rowM[mc]) * rowInvS[mc];
            o.w = __expf(v.w - rowM[md]) * rowInvS[md];
        }
        P4[i] = o;
    }
}

// ---------------------------------------------------------------------------
extern "C" void kernel_launch(void* const* d_in, const int* in_sizes, int n_in,
                              void* d_out, int out_size, void* d_ws, size_t ws_size,
                              hipStream_t stream) {
    const int*   tok    = (const int*)d_in[0];
    const float* emb    = (const float*)d_in[1];
    const float* gate_k = (const float*)d_in[2];
    const float* gate_b = (const float*)d_in[3];
    const float* cand_k = (const float*)d_in[4];
    const float* cand_b = (const float*)d_in[5];
    const float* W      = (const float*)d_in[6];
    const float* bias   = (const float*)d_in[7];

    float* logits = (float*)d_out;
    float* probs  = logits + (size_t)GM * GV;

    float* ws = (float*)d_ws;
    float* gruout = ws;                                        // 640,000 f32
    unsigned short* Ap = (unsigned short*)(gruout + 640000);   // 40*4*8192 bf16
    unsigned short* Wp = Ap + (size_t)MT * 4 * 8192;           // 393*4*8192 bf16
    float* pmax    = (float*)(Wp + (size_t)NT * 4 * 8192);
    float* psum    = pmax + (size_t)GM * NT;
    float* rowM    = psum + (size_t)GM * NT;
    float* rowInvS = rowM + GM;

    // GRU scratch OVERLAYS the pmax region (2.56M floats < 3.93M; pmax is
    // written only by the later GEMM, stream-ordered after the GRU phase).
    float* XBH0 = pmax;                 // 640,000 (XB, then H0)
    float* GX   = pmax + 640000;        // 1,280,000
    float* CX   = pmax + 1920000;       // 640,000

    // ---- GRU phase ----
    gather_kernel<<<(GM * 32 + 255) / 256, 256, 0, stream>>>(tok, emb, XBH0);
    xpart_kernel<<<(GM + 15) / 16, 256, 0, stream>>>(XBH0, gate_k, cand_k, GX, CX);
    scan_kernel<<<GB, 1024, 0, stream>>>(GX, CX,
        gate_k + 128 * GH2, cand_k + 128 * GH, gate_b, cand_b, XBH0 /* = H0 */);
    xpart_kernel<<<(GM + 15) / 16, 256, 0, stream>>>(XBH0,
        gate_k + GH2 * GH2, cand_k + GH2 * GH, GX, CX);
    scan_kernel<<<GB, 1024, 0, stream>>>(GX, CX,
        gate_k + GH2 * GH2 + 128 * GH2, cand_k + GH2 * GH + 128 * GH,
        gate_b + GH2, cand_b + GH, gruout);

    // ---- logits + softmax phase (unchanged from r10) ----
    prep_kernel<<<(MT * 4 * 128 + 255) / 256, 256, 0, stream>>>(gruout, Ap, MT, GM);
    prep_kernel<<<(NT * 4 * 128 + 255) / 256, 256, 0, stream>>>(W, Wp, NT, GV);

    dim3 g2(MT, NT);   // m-tile fastest: W-tile L2/L3 locality
    mfma_logits_kernel<<<g2, 256, 0, stream>>>(Ap, Wp, bias, logits, pmax, psum);

    reduce_kernel<<<GM, 64, 0, stream>>>(pmax, psum, rowM, rowInvS);

    probs_kernel<<<4096, 256, 0, stream>>>(logits, rowM, rowInvS, probs);
}